// Round 1
// baseline (111.026 us; speedup 1.0000x reference)
//
#include <hip/hip_runtime.h>
#include <math.h>

#define PATCHES 196
#define MLP_ROWS 8

// ---------------------------------------------------------------------------
// Stage 1: quanvolution. One thread per (batch, patch). 16-amplitude real
// statevector in registers; RY = 8 butterfly pairs; CNOT = register permute
// (free after unrolling); measure-Z = signed sum of squared amps.
// Wire w corresponds to bitmask (8 >> w) in the flat 16-state index.
// ---------------------------------------------------------------------------

__device__ __forceinline__ void apply_ry(float st[16], int bit, float c, float s) {
#pragma unroll
  for (int i = 0; i < 16; ++i) {
    if (!(i & bit)) {
      int j = i | bit;
      float a0 = st[i], a1 = st[j];
      st[i] = c * a0 - s * a1;
      st[j] = s * a0 + c * a1;
    }
  }
}

__device__ __forceinline__ void apply_cnot(float st[16], int cb, int tb) {
#pragma unroll
  for (int i = 0; i < 16; ++i) {
    if ((i & cb) && !(i & tb)) {
      int j = i | tb;
      float t = st[i]; st[i] = st[j]; st[j] = t;
    }
  }
}

__global__ __launch_bounds__(256) void quanv_kernel(
    const float* __restrict__ x, const float* __restrict__ theta,
    float* __restrict__ feats, int total) {
  __shared__ float tc[8], ts[8];
  if (threadIdx.x < 8) {
    float c, s;
    sincosf(0.5f * theta[threadIdx.x], &s, &c);
    tc[threadIdx.x] = c;
    ts[threadIdx.x] = s;
  }
  __syncthreads();

  int gid = blockIdx.x * 256 + threadIdx.x;
  if (gid >= total) return;

  int b = gid / PATCHES;
  int p = gid - b * PATCHES;
  int pr = p / 14;
  int pc = p - pr * 14;

  // patch values: x[b, 2pr, 2pc], x[b, 2pr, 2pc+1], x[b, 2pr+1, 2pc], x[b, 2pr+1, 2pc+1]
  const float* xb = x + (size_t)b * 784 + pr * 56 + pc * 2;
  float v0 = xb[0], v1 = xb[1], v2 = xb[28], v3 = xb[29];

  float st[16];
#pragma unroll
  for (int i = 0; i < 16; ++i) st[i] = 0.f;
  st[0] = 1.f;

  float c, s;
  sincosf(0.5f * v0, &s, &c); apply_ry(st, 8, c, s);
  sincosf(0.5f * v1, &s, &c); apply_ry(st, 4, c, s);
  sincosf(0.5f * v2, &s, &c); apply_ry(st, 2, c, s);
  sincosf(0.5f * v3, &s, &c); apply_ry(st, 1, c, s);

#pragma unroll
  for (int l = 0; l < 2; ++l) {
    apply_ry(st, 8, tc[l * 4 + 0], ts[l * 4 + 0]);
    apply_ry(st, 4, tc[l * 4 + 1], ts[l * 4 + 1]);
    apply_ry(st, 2, tc[l * 4 + 2], ts[l * 4 + 2]);
    apply_ry(st, 1, tc[l * 4 + 3], ts[l * 4 + 3]);
    apply_cnot(st, 8, 4);  // CNOT(0,1)
    apply_cnot(st, 4, 2);  // CNOT(1,2)
    apply_cnot(st, 2, 1);  // CNOT(2,3)
    apply_cnot(st, 1, 8);  // CNOT(3,0)
  }

  float m0 = 0.f, m1 = 0.f, m2 = 0.f, m3 = 0.f;
#pragma unroll
  for (int i = 0; i < 16; ++i) {
    float p2 = st[i] * st[i];
    m0 += (i & 8) ? -p2 : p2;
    m1 += (i & 4) ? -p2 : p2;
    m2 += (i & 2) ? -p2 : p2;
    m3 += (i & 1) ? -p2 : p2;
  }

  float4 m;
  m.x = m0; m.y = m1; m.z = m2; m.w = m3;
  reinterpret_cast<float4*>(feats)[gid] = m;  // feats[b*784 + p*4 + w]
}

// ---------------------------------------------------------------------------
// Stage 2: fused MLP + log_softmax. One block = 8 rows of the batch.
// feats rows staged in LDS (broadcast reads); W1 column loads coalesced
// (lane -> consecutive column). Epilogue: h in LDS -> 80 threads do the
// 128x10 GEMM -> 8 threads do log_softmax.
// ---------------------------------------------------------------------------

__global__ __launch_bounds__(256) void mlp_kernel(
    const float* __restrict__ feats, const float* __restrict__ W1,
    const float* __restrict__ b1, const float* __restrict__ W2,
    const float* __restrict__ b2, float* __restrict__ out) {
  __shared__ __align__(16) float fs[MLP_ROWS * 784];
  __shared__ float hs[MLP_ROWS * 128];
  __shared__ float ls[MLP_ROWS * 10];

  const int tid = threadIdx.x;
  const int row0 = blockIdx.x * MLP_ROWS;

  // stage 8 consecutive feats rows (contiguous 6272 floats) into LDS
  const float* src = feats + (size_t)row0 * 784;
  for (int idx = tid; idx < MLP_ROWS * 784; idx += 256) fs[idx] = src[idx];
  __syncthreads();

  const int j = tid & 127;   // output column of W1
  const int rg = tid >> 7;   // row group: rows rg*4 .. rg*4+3

  const float* fb0 = fs + (rg * 4 + 0) * 784;
  const float* fb1 = fs + (rg * 4 + 1) * 784;
  const float* fb2 = fs + (rg * 4 + 2) * 784;
  const float* fb3 = fs + (rg * 4 + 3) * 784;

  float acc0 = 0.f, acc1 = 0.f, acc2 = 0.f, acc3 = 0.f;

  for (int i4 = 0; i4 < 196; ++i4) {
    const float4 f0 = *reinterpret_cast<const float4*>(fb0 + i4 * 4);
    const float4 f1 = *reinterpret_cast<const float4*>(fb1 + i4 * 4);
    const float4 f2 = *reinterpret_cast<const float4*>(fb2 + i4 * 4);
    const float4 f3 = *reinterpret_cast<const float4*>(fb3 + i4 * 4);
    const float* wp = W1 + (size_t)(i4 * 4) * 128 + j;
    const float w0 = wp[0];
    const float w1 = wp[128];
    const float w2 = wp[256];
    const float w3 = wp[384];
    acc0 = fmaf(f0.x, w0, fmaf(f0.y, w1, fmaf(f0.z, w2, fmaf(f0.w, w3, acc0))));
    acc1 = fmaf(f1.x, w0, fmaf(f1.y, w1, fmaf(f1.z, w2, fmaf(f1.w, w3, acc1))));
    acc2 = fmaf(f2.x, w0, fmaf(f2.y, w1, fmaf(f2.z, w2, fmaf(f2.w, w3, acc2))));
    acc3 = fmaf(f3.x, w0, fmaf(f3.y, w1, fmaf(f3.z, w2, fmaf(f3.w, w3, acc3))));
  }

  const float bj = b1[j];
  hs[(rg * 4 + 0) * 128 + j] = fmaxf(acc0 + bj, 0.f);
  hs[(rg * 4 + 1) * 128 + j] = fmaxf(acc1 + bj, 0.f);
  hs[(rg * 4 + 2) * 128 + j] = fmaxf(acc2 + bj, 0.f);
  hs[(rg * 4 + 3) * 128 + j] = fmaxf(acc3 + bj, 0.f);
  __syncthreads();

  // second GEMM: 8 rows x 10 classes = 80 dot products of length 128
  if (tid < MLP_ROWS * 10) {
    const int r = tid / 10;
    const int k = tid - r * 10;
    float a = b2[k];
    const float* hr = hs + r * 128;
#pragma unroll 8
    for (int jj = 0; jj < 128; ++jj) a = fmaf(hr[jj], W2[jj * 10 + k], a);
    ls[tid] = a;
  }
  __syncthreads();

  // log_softmax per row
  if (tid < MLP_ROWS) {
    const int r = tid;
    float mx = ls[r * 10];
#pragma unroll
    for (int k = 1; k < 10; ++k) mx = fmaxf(mx, ls[r * 10 + k]);
    float sum = 0.f;
#pragma unroll
    for (int k = 0; k < 10; ++k) sum += expf(ls[r * 10 + k] - mx);
    const float lse = mx + logf(sum);
    float* orow = out + (size_t)(row0 + r) * 10;
#pragma unroll
    for (int k = 0; k < 10; ++k) orow[k] = ls[r * 10 + k] - lse;
  }
}

extern "C" void kernel_launch(void* const* d_in, const int* in_sizes, int n_in,
                              void* d_out, int out_size, void* d_ws, size_t ws_size,
                              hipStream_t stream) {
  const float* x     = (const float*)d_in[0];
  const float* theta = (const float*)d_in[1];
  const float* W1    = (const float*)d_in[2];
  const float* b1    = (const float*)d_in[3];
  const float* W2    = (const float*)d_in[4];
  const float* b2    = (const float*)d_in[5];
  float* out = (float*)d_out;

  const int B = in_sizes[0] / 784;
  float* feats = (float*)d_ws;  // B*784 floats = 12.8 MB

  const int total = B * PATCHES;
  quanv_kernel<<<(total + 255) / 256, 256, 0, stream>>>(x, theta, feats, total);
  mlp_kernel<<<B / MLP_ROWS, 256, 0, stream>>>(feats, W1, b1, W2, b2, out);
}

// Round 2
// 95.838 us; speedup vs baseline: 1.1585x; 1.1585x over previous
//
#include <hip/hip_runtime.h>
#include <math.h>

#define PATCHES 196
#define KPAD 800          // 784 padded to 25*32 for MFMA K-loop
#define MROWS 16          // batch rows per GEMM block

typedef short short8 __attribute__((ext_vector_type(8)));
typedef float f32x4 __attribute__((ext_vector_type(4)));

__device__ __forceinline__ unsigned short f2bf(float f) {
  union { float f; unsigned u; } x; x.f = f;
  unsigned r = x.u + 0x7fff + ((x.u >> 16) & 1);  // round-to-nearest-even
  return (unsigned short)(r >> 16);
}

// ---------------------------------------------------------------------------
// Stage 0: W1^T in bf16, zero-padded K: w1t[n][k] = bf16(W1[k][n]), k<784
// ---------------------------------------------------------------------------
__global__ __launch_bounds__(256) void w1t_kernel(
    const float* __restrict__ W1, unsigned short* __restrict__ w1t) {
  int idx = blockIdx.x * 256 + threadIdx.x;
  if (idx >= 128 * KPAD) return;
  int n = idx / KPAD;
  int k = idx - n * KPAD;
  float v = (k < 784) ? W1[k * 128 + n] : 0.f;
  w1t[idx] = f2bf(v);
}

// ---------------------------------------------------------------------------
// Stage 1: quanvolution. One thread per (batch, patch); 16-amp statevector in
// registers; hardware trig (v_sin/v_cos). Writes feats as bf16 [B, KPAD].
// ---------------------------------------------------------------------------
__device__ __forceinline__ void apply_ry(float st[16], int bit, float c, float s) {
#pragma unroll
  for (int i = 0; i < 16; ++i) {
    if (!(i & bit)) {
      int j = i | bit;
      float a0 = st[i], a1 = st[j];
      st[i] = c * a0 - s * a1;
      st[j] = s * a0 + c * a1;
    }
  }
}

__device__ __forceinline__ void apply_cnot(float st[16], int cb, int tb) {
#pragma unroll
  for (int i = 0; i < 16; ++i) {
    if ((i & cb) && !(i & tb)) {
      int j = i | tb;
      float t = st[i]; st[i] = st[j]; st[j] = t;
    }
  }
}

__global__ __launch_bounds__(256) void quanv_kernel(
    const float* __restrict__ x, const float* __restrict__ theta,
    unsigned short* __restrict__ feats, int total) {
  __shared__ float tc[8], ts[8];
  if (threadIdx.x < 8) {
    float a = 0.5f * theta[threadIdx.x];
    tc[threadIdx.x] = __cosf(a);
    ts[threadIdx.x] = __sinf(a);
  }
  __syncthreads();

  int gid = blockIdx.x * 256 + threadIdx.x;
  if (gid >= total) return;

  int b = gid / PATCHES;
  int p = gid - b * PATCHES;
  int pr = p / 14;
  int pc = p - pr * 14;

  const float* xb = x + (size_t)b * 784 + pr * 56 + pc * 2;
  float v0 = xb[0], v1 = xb[1], v2 = xb[28], v3 = xb[29];

  float st[16];
#pragma unroll
  for (int i = 0; i < 16; ++i) st[i] = 0.f;
  st[0] = 1.f;

  apply_ry(st, 8, __cosf(0.5f * v0), __sinf(0.5f * v0));
  apply_ry(st, 4, __cosf(0.5f * v1), __sinf(0.5f * v1));
  apply_ry(st, 2, __cosf(0.5f * v2), __sinf(0.5f * v2));
  apply_ry(st, 1, __cosf(0.5f * v3), __sinf(0.5f * v3));

#pragma unroll
  for (int l = 0; l < 2; ++l) {
    apply_ry(st, 8, tc[l * 4 + 0], ts[l * 4 + 0]);
    apply_ry(st, 4, tc[l * 4 + 1], ts[l * 4 + 1]);
    apply_ry(st, 2, tc[l * 4 + 2], ts[l * 4 + 2]);
    apply_ry(st, 1, tc[l * 4 + 3], ts[l * 4 + 3]);
    apply_cnot(st, 8, 4);
    apply_cnot(st, 4, 2);
    apply_cnot(st, 2, 1);
    apply_cnot(st, 1, 8);
  }

  float m0 = 0.f, m1 = 0.f, m2 = 0.f, m3 = 0.f;
#pragma unroll
  for (int i = 0; i < 16; ++i) {
    float p2 = st[i] * st[i];
    m0 += (i & 8) ? -p2 : p2;
    m1 += (i & 4) ? -p2 : p2;
    m2 += (i & 2) ? -p2 : p2;
    m3 += (i & 1) ? -p2 : p2;
  }

  ushort4 out;
  out.x = f2bf(m0); out.y = f2bf(m1); out.z = f2bf(m2); out.w = f2bf(m3);
  *reinterpret_cast<ushort4*>(feats + (size_t)b * KPAD + p * 4) = out;

  // zero the K padding (cols 784..799): 4 threads per batch row cover 16
  if (p < 4) {
    ushort4 z; z.x = z.y = z.z = z.w = 0;
    *reinterpret_cast<ushort4*>(feats + (size_t)b * KPAD + 784 + p * 4) = z;
  }
}

// ---------------------------------------------------------------------------
// Stage 2: MFMA bf16 GEMM1 (16 rows x 128 cols x 784) fused with bias+relu,
// GEMM2 (128x10) and log_softmax. Block = 256 thr = 4 waves; wave w handles
// n-tiles {2w, 2w+1}. A/B frags loaded directly from global (L2-resident);
// no LDS in the K-loop. C/D layout: col=lane&15, row=(lane>>4)*4+reg.
// A frag: m=lane&15, k=(lane>>4)*8+j. B frag (from W1^T): n=lane&15, same k.
// ---------------------------------------------------------------------------
__global__ __launch_bounds__(256) void gemm_kernel(
    const unsigned short* __restrict__ feats, const unsigned short* __restrict__ w1t,
    const float* __restrict__ b1, const float* __restrict__ W2,
    const float* __restrict__ b2, float* __restrict__ out) {
  __shared__ float hs[MROWS * 132];  // stride 132: (4r+j)%32 -> 2-way max (free)
  __shared__ float ls[MROWS * 10];

  const int tid = threadIdx.x;
  const int lane = tid & 63;
  const int wave = tid >> 6;
  const int m = lane & 15;      // row within tile (A) / col within tile (B, C)
  const int quad = lane >> 4;   // k-group for A/B, row-group for C
  const int row0 = blockIdx.x * MROWS;

  const unsigned short* ap = feats + (size_t)(row0 + m) * KPAD + quad * 8;
  const unsigned short* bp0 = w1t + (size_t)((wave * 2 + 0) * 16 + m) * KPAD + quad * 8;
  const unsigned short* bp1 = w1t + (size_t)((wave * 2 + 1) * 16 + m) * KPAD + quad * 8;

  f32x4 acc0 = {0.f, 0.f, 0.f, 0.f};
  f32x4 acc1 = {0.f, 0.f, 0.f, 0.f};

#pragma unroll 5
  for (int k0 = 0; k0 < KPAD; k0 += 32) {
    short8 a  = *reinterpret_cast<const short8*>(ap + k0);
    short8 b0 = *reinterpret_cast<const short8*>(bp0 + k0);
    short8 b1f = *reinterpret_cast<const short8*>(bp1 + k0);
    acc0 = __builtin_amdgcn_mfma_f32_16x16x32_bf16(a, b0, acc0, 0, 0, 0);
    acc1 = __builtin_amdgcn_mfma_f32_16x16x32_bf16(a, b1f, acc1, 0, 0, 0);
  }

  // epilogue: bias + relu -> hs
  {
    const int col0 = (wave * 2 + 0) * 16 + m;
    const int col1 = (wave * 2 + 1) * 16 + m;
    const float bc0 = b1[col0];
    const float bc1 = b1[col1];
#pragma unroll
    for (int r = 0; r < 4; ++r) {
      const int row = quad * 4 + r;
      hs[row * 132 + col0] = fmaxf(acc0[r] + bc0, 0.f);
      hs[row * 132 + col1] = fmaxf(acc1[r] + bc1, 0.f);
    }
  }
  __syncthreads();

  // GEMM2: 16 rows x 10 classes
  if (tid < MROWS * 10) {
    const int r = tid / 10;
    const int k = tid - r * 10;
    float a = b2[k];
    const float* hr = hs + r * 132;
#pragma unroll 8
    for (int jj = 0; jj < 128; ++jj) a = fmaf(hr[jj], W2[jj * 10 + k], a);
    ls[tid] = a;
  }
  __syncthreads();

  // log_softmax per row
  if (tid < MROWS) {
    const int r = tid;
    float mx = ls[r * 10];
#pragma unroll
    for (int k = 1; k < 10; ++k) mx = fmaxf(mx, ls[r * 10 + k]);
    float sum = 0.f;
#pragma unroll
    for (int k = 0; k < 10; ++k) sum += expf(ls[r * 10 + k] - mx);
    const float lse = mx + logf(sum);
    float* orow = out + (size_t)(row0 + r) * 10;
#pragma unroll
    for (int k = 0; k < 10; ++k) orow[k] = ls[r * 10 + k] - lse;
  }
}

extern "C" void kernel_launch(void* const* d_in, const int* in_sizes, int n_in,
                              void* d_out, int out_size, void* d_ws, size_t ws_size,
                              hipStream_t stream) {
  const float* x     = (const float*)d_in[0];
  const float* theta = (const float*)d_in[1];
  const float* W1    = (const float*)d_in[2];
  const float* b1    = (const float*)d_in[3];
  const float* W2    = (const float*)d_in[4];
  const float* b2    = (const float*)d_in[5];
  float* out = (float*)d_out;

  const int B = in_sizes[0] / 784;

  unsigned short* feats = (unsigned short*)d_ws;            // B*KPAD bf16 = 6.55 MB
  unsigned short* w1t   = feats + (size_t)B * KPAD;          // 128*KPAD bf16 = 0.2 MB

  w1t_kernel<<<(128 * KPAD + 255) / 256, 256, 0, stream>>>(W1, w1t);
  const int total = B * PATCHES;
  quanv_kernel<<<(total + 255) / 256, 256, 0, stream>>>(x, theta, feats, total);
  gemm_kernel<<<B / MROWS, 256, 0, stream>>>(feats, w1t, b1, W2, b2, out);
}

// Round 3
// 94.148 us; speedup vs baseline: 1.1793x; 1.0180x over previous
//
#include <hip/hip_runtime.h>
#include <math.h>

#define PATCHES 196
#define KPAD 800           // 784 padded to 25*32 for MFMA K-loop
#define MROWS 16           // batch rows per block
#define CIRC (MROWS * PATCHES)   // 3136 circuits per block
#define FRAG_ELEMS (25 * 64 * 8) // 12800 elems per 16-row (or 16-col) group

typedef short short8 __attribute__((ext_vector_type(8)));
typedef float f32x4 __attribute__((ext_vector_type(4)));

__device__ __forceinline__ unsigned short f2bf(float f) {
  union { float f; unsigned u; } x; x.f = f;
  unsigned r = x.u + 0x7fff + ((x.u >> 16) & 1);  // round-to-nearest-even
  return (unsigned short)(r >> 16);
}

// fragment-order element offset for (group-local row/col m, k):
// elem = (ki*64 + quad*16 + m)*8 + j   with ki=k>>5, quad=(k&31)>>3, j=k&7
// so that lane l at iter ki reads elems (ki*64+l)*8 .. +7  (16B, lane-contiguous)

// ---------------------------------------------------------------------------
// Stage 0: pack W1^T (bf16, K zero-padded) into B-fragment order.
// ---------------------------------------------------------------------------
__global__ __launch_bounds__(256) void w1t_pack_kernel(
    const float* __restrict__ W1, unsigned short* __restrict__ w1p) {
  int idx = blockIdx.x * 256 + threadIdx.x;
  if (idx >= 128 * KPAD) return;
  int n = idx / KPAD;
  int k = idx - n * KPAD;
  float v = (k < 784) ? W1[k * 128 + n] : 0.f;
  int ntile = n >> 4;
  int ki = k >> 5;
  int quad = (k & 31) >> 3;
  int j = k & 7;
  w1p[ntile * FRAG_ELEMS + (ki * 64 + quad * 16 + (n & 15)) * 8 + j] = f2bf(v);
}

// ---------------------------------------------------------------------------
// Fused kernel: quanv (16 rows x 196 circuits -> LDS in A-fragment order)
// + MFMA GEMM1 + bias/relu + GEMM2 + log_softmax.
// Block = 256 thr = 4 waves; wave w owns n-tiles {2w, 2w+1}.
// ---------------------------------------------------------------------------
__device__ __forceinline__ void apply_ry(float st[16], int bit, float c, float s) {
#pragma unroll
  for (int i = 0; i < 16; ++i) {
    if (!(i & bit)) {
      int j = i | bit;
      float a0 = st[i], a1 = st[j];
      st[i] = c * a0 - s * a1;
      st[j] = s * a0 + c * a1;
    }
  }
}

__device__ __forceinline__ void apply_cnot(float st[16], int cb, int tb) {
#pragma unroll
  for (int i = 0; i < 16; ++i) {
    if ((i & cb) && !(i & tb)) {
      int j = i | tb;
      float t = st[i]; st[i] = st[j]; st[j] = t;
    }
  }
}

__global__ __launch_bounds__(256) void fused_kernel(
    const float* __restrict__ x, const float* __restrict__ theta,
    const unsigned short* __restrict__ w1p, const float* __restrict__ b1,
    const float* __restrict__ W2, const float* __restrict__ b2,
    float* __restrict__ out) {
  __shared__ unsigned short afr[FRAG_ELEMS];     // 25.6 KB: A tile, frag order
  __shared__ float tc[8], ts[8];
  __shared__ float hs[MROWS * 132];              // stride 132: conflict-light
  __shared__ float ls[MROWS * 10];

  const int tid = threadIdx.x;
  const int row0 = blockIdx.x * MROWS;

  if (tid < 8) {
    float a = 0.5f * theta[tid];
    tc[tid] = __cosf(a);
    ts[tid] = __sinf(a);
  }
  // zero-pad k = 784..799 (ki=24, quads 2..3) for all 16 rows: 64 x 8B
  if (tid < 64) {
    int m = tid & 15;
    int qs = tid >> 4;                 // 0..3
    int quad = 2 + (qs >> 1);
    int j0 = (qs & 1) * 4;
    ushort4 z; z.x = z.y = z.z = z.w = 0;
    *reinterpret_cast<ushort4*>(afr + (24 * 64 + quad * 16 + m) * 8 + j0) = z;
  }
  __syncthreads();

  // ---- phase 1: circuits -> LDS (A-fragment order) ----
  for (int c = tid; c < CIRC; c += 256) {
    int bl = c / PATCHES;              // local row 0..15
    int p = c - bl * PATCHES;
    int pr = p / 14;
    int pc = p - pr * 14;

    const float* xb = x + (size_t)(row0 + bl) * 784 + pr * 56 + pc * 2;
    float v0 = xb[0], v1 = xb[1], v2 = xb[28], v3 = xb[29];

    float st[16];
#pragma unroll
    for (int i = 0; i < 16; ++i) st[i] = 0.f;
    st[0] = 1.f;

    apply_ry(st, 8, __cosf(0.5f * v0), __sinf(0.5f * v0));
    apply_ry(st, 4, __cosf(0.5f * v1), __sinf(0.5f * v1));
    apply_ry(st, 2, __cosf(0.5f * v2), __sinf(0.5f * v2));
    apply_ry(st, 1, __cosf(0.5f * v3), __sinf(0.5f * v3));

#pragma unroll
    for (int l = 0; l < 2; ++l) {
      apply_ry(st, 8, tc[l * 4 + 0], ts[l * 4 + 0]);
      apply_ry(st, 4, tc[l * 4 + 1], ts[l * 4 + 1]);
      apply_ry(st, 2, tc[l * 4 + 2], ts[l * 4 + 2]);
      apply_ry(st, 1, tc[l * 4 + 3], ts[l * 4 + 3]);
      apply_cnot(st, 8, 4);
      apply_cnot(st, 4, 2);
      apply_cnot(st, 2, 1);
      apply_cnot(st, 1, 8);
    }

    float m0 = 0.f, m1 = 0.f, m2 = 0.f, m3 = 0.f;
#pragma unroll
    for (int i = 0; i < 16; ++i) {
      float p2 = st[i] * st[i];
      m0 += (i & 8) ? -p2 : p2;
      m1 += (i & 4) ? -p2 : p2;
      m2 += (i & 2) ? -p2 : p2;
      m3 += (i & 1) ? -p2 : p2;
    }

    // k = 4p .. 4p+3 for row bl -> fragment-order 8B write
    int K = p * 4;
    int ki = K >> 5;
    int quad = (K & 31) >> 3;
    int j0 = K & 7;                    // 0 or 4
    ushort4 o;
    o.x = f2bf(m0); o.y = f2bf(m1); o.z = f2bf(m2); o.w = f2bf(m3);
    *reinterpret_cast<ushort4*>(afr + (ki * 64 + quad * 16 + bl) * 8 + j0) = o;
  }
  __syncthreads();

  // ---- phase 2: MFMA K-loop (A from LDS, B coalesced from global) ----
  const int lane = tid & 63;
  const int wave = tid >> 6;
  const int m = lane & 15;
  const int quad = lane >> 4;

  const unsigned short* bp0 = w1p + (size_t)(wave * 2 + 0) * FRAG_ELEMS + lane * 8;
  const unsigned short* bp1 = w1p + (size_t)(wave * 2 + 1) * FRAG_ELEMS + lane * 8;
  const unsigned short* apl = afr + lane * 8;

  f32x4 acc0 = {0.f, 0.f, 0.f, 0.f};
  f32x4 acc1 = {0.f, 0.f, 0.f, 0.f};

#pragma unroll 5
  for (int ki = 0; ki < 25; ++ki) {
    short8 a  = *reinterpret_cast<const short8*>(apl + ki * 512);
    short8 b0 = *reinterpret_cast<const short8*>(bp0 + ki * 512);
    short8 b1f = *reinterpret_cast<const short8*>(bp1 + ki * 512);
    acc0 = __builtin_amdgcn_mfma_f32_16x16x32_bf16(a, b0, acc0, 0, 0, 0);
    acc1 = __builtin_amdgcn_mfma_f32_16x16x32_bf16(a, b1f, acc1, 0, 0, 0);
  }

  // ---- epilogue: bias + relu -> hs ----
  {
    const int col0 = (wave * 2 + 0) * 16 + m;
    const int col1 = (wave * 2 + 1) * 16 + m;
    const float bc0 = b1[col0];
    const float bc1 = b1[col1];
#pragma unroll
    for (int r = 0; r < 4; ++r) {
      const int row = quad * 4 + r;
      hs[row * 132 + col0] = fmaxf(acc0[r] + bc0, 0.f);
      hs[row * 132 + col1] = fmaxf(acc1[r] + bc1, 0.f);
    }
  }
  __syncthreads();

  // ---- GEMM2: 16 rows x 10 classes ----
  if (tid < MROWS * 10) {
    const int r = tid / 10;
    const int k = tid - r * 10;
    float a = b2[k];
    const float* hr = hs + r * 132;
#pragma unroll 8
    for (int jj = 0; jj < 128; ++jj) a = fmaf(hr[jj], W2[jj * 10 + k], a);
    ls[tid] = a;
  }
  __syncthreads();

  // ---- log_softmax ----
  if (tid < MROWS) {
    const int r = tid;
    float mx = ls[r * 10];
#pragma unroll
    for (int k = 1; k < 10; ++k) mx = fmaxf(mx, ls[r * 10 + k]);
    float sum = 0.f;
#pragma unroll
    for (int k = 0; k < 10; ++k) sum += expf(ls[r * 10 + k] - mx);
    const float lse = mx + logf(sum);
    float* orow = out + (size_t)(row0 + r) * 10;
#pragma unroll
    for (int k = 0; k < 10; ++k) orow[k] = ls[r * 10 + k] - lse;
  }
}

extern "C" void kernel_launch(void* const* d_in, const int* in_sizes, int n_in,
                              void* d_out, int out_size, void* d_ws, size_t ws_size,
                              hipStream_t stream) {
  const float* x     = (const float*)d_in[0];
  const float* theta = (const float*)d_in[1];
  const float* W1    = (const float*)d_in[2];
  const float* b1    = (const float*)d_in[3];
  const float* W2    = (const float*)d_in[4];
  const float* b2    = (const float*)d_in[5];
  float* out = (float*)d_out;

  const int B = in_sizes[0] / 784;

  unsigned short* w1p = (unsigned short*)d_ws;   // 128*KPAD bf16 = 200 KB

  w1t_pack_kernel<<<(128 * KPAD + 255) / 256, 256, 0, stream>>>(W1, w1p);
  fused_kernel<<<B / MROWS, 256, 0, stream>>>(x, theta, w1p, b1, W2, b2, out);
}

// Round 4
// 93.337 us; speedup vs baseline: 1.1895x; 1.0087x over previous
//
#include <hip/hip_runtime.h>
#include <math.h>

#define PATCHES 196
#define KPAD 800                 // 784 padded to 25*32 for MFMA K-loop
#define MROWS 16                 // batch rows per gemm block
#define FRAG_ELEMS (25 * 64 * 8) // elems per 16-col B tile in fragment order

typedef short short8 __attribute__((ext_vector_type(8)));
typedef float f32x4 __attribute__((ext_vector_type(4)));

__device__ __forceinline__ unsigned short f2bf(float f) {
  union { float f; unsigned u; } x; x.f = f;
  unsigned r = x.u + 0x7fff + ((x.u >> 16) & 1);  // round-to-nearest-even
  return (unsigned short)(r >> 16);
}

// ---------------------------------------------------------------------------
// Stage 0: pack W1^T (bf16, K zero-padded) into B-fragment order:
// elem = ntile*FRAG_ELEMS + (ki*64 + quad*16 + n15)*8 + j  (lane-contiguous)
// ---------------------------------------------------------------------------
__global__ __launch_bounds__(256) void w1t_pack_kernel(
    const float* __restrict__ W1, unsigned short* __restrict__ w1p) {
  int idx = blockIdx.x * 256 + threadIdx.x;
  if (idx >= 128 * KPAD) return;
  int n = idx / KPAD;
  int k = idx - n * KPAD;
  float v = (k < 784) ? W1[k * 128 + n] : 0.f;
  int ki = k >> 5;
  int quad = (k & 31) >> 3;
  int j = k & 7;
  w1p[(n >> 4) * FRAG_ELEMS + (ki * 64 + quad * 16 + (n & 15)) * 8 + j] = f2bf(v);
}

// ---------------------------------------------------------------------------
// Stage 1: quanvolution, one thread per (batch, patch). Full occupancy
// (3136 blocks). Row-major bf16 feats [B, KPAD]: coalesced 8B writes, and
// row-major is directly A-fragment-readable by the gemm.
// ---------------------------------------------------------------------------
__device__ __forceinline__ void apply_ry(float st[16], int bit, float c, float s) {
#pragma unroll
  for (int i = 0; i < 16; ++i) {
    if (!(i & bit)) {
      int j = i | bit;
      float a0 = st[i], a1 = st[j];
      st[i] = c * a0 - s * a1;
      st[j] = s * a0 + c * a1;
    }
  }
}

__device__ __forceinline__ void apply_cnot(float st[16], int cb, int tb) {
#pragma unroll
  for (int i = 0; i < 16; ++i) {
    if ((i & cb) && !(i & tb)) {
      int j = i | tb;
      float t = st[i]; st[i] = st[j]; st[j] = t;
    }
  }
}

__global__ __launch_bounds__(256) void quanv_kernel(
    const float* __restrict__ x, const float* __restrict__ theta,
    unsigned short* __restrict__ feats, int total) {
  __shared__ float tc[8], ts[8];
  if (threadIdx.x < 8) {
    float a = 0.5f * theta[threadIdx.x];
    tc[threadIdx.x] = __cosf(a);
    ts[threadIdx.x] = __sinf(a);
  }
  __syncthreads();

  int gid = blockIdx.x * 256 + threadIdx.x;
  if (gid >= total) return;

  int b = gid / PATCHES;
  int p = gid - b * PATCHES;
  int pr = p / 14;
  int pc = p - pr * 14;

  const float* xb = x + (size_t)b * 784 + pr * 56 + pc * 2;
  float v0 = xb[0], v1 = xb[1], v2 = xb[28], v3 = xb[29];

  float st[16];
#pragma unroll
  for (int i = 0; i < 16; ++i) st[i] = 0.f;
  st[0] = 1.f;

  apply_ry(st, 8, __cosf(0.5f * v0), __sinf(0.5f * v0));
  apply_ry(st, 4, __cosf(0.5f * v1), __sinf(0.5f * v1));
  apply_ry(st, 2, __cosf(0.5f * v2), __sinf(0.5f * v2));
  apply_ry(st, 1, __cosf(0.5f * v3), __sinf(0.5f * v3));

#pragma unroll
  for (int l = 0; l < 2; ++l) {
    apply_ry(st, 8, tc[l * 4 + 0], ts[l * 4 + 0]);
    apply_ry(st, 4, tc[l * 4 + 1], ts[l * 4 + 1]);
    apply_ry(st, 2, tc[l * 4 + 2], ts[l * 4 + 2]);
    apply_ry(st, 1, tc[l * 4 + 3], ts[l * 4 + 3]);
    apply_cnot(st, 8, 4);
    apply_cnot(st, 4, 2);
    apply_cnot(st, 2, 1);
    apply_cnot(st, 1, 8);
  }

  float m0 = 0.f, m1 = 0.f, m2 = 0.f, m3 = 0.f;
#pragma unroll
  for (int i = 0; i < 16; ++i) {
    float p2 = st[i] * st[i];
    m0 += (i & 8) ? -p2 : p2;
    m1 += (i & 4) ? -p2 : p2;
    m2 += (i & 2) ? -p2 : p2;
    m3 += (i & 1) ? -p2 : p2;
  }

  ushort4 o;
  o.x = f2bf(m0); o.y = f2bf(m1); o.z = f2bf(m2); o.w = f2bf(m3);
  *reinterpret_cast<ushort4*>(feats + (size_t)b * KPAD + p * 4) = o;

  if (p < 4) {  // zero K padding 784..799
    ushort4 z; z.x = z.y = z.z = z.w = 0;
    *reinterpret_cast<ushort4*>(feats + (size_t)b * KPAD + 784 + p * 4) = z;
  }
}

// ---------------------------------------------------------------------------
// Stage 2: MFMA GEMM1 + bias/relu + GEMM2 + log_softmax.
// Block = 512 thr = 8 waves (2 waves/SIMD); wave w owns n-tile w (16 cols).
// A: row-major feats, lane(m,quad) reads 16 contiguous B at m*KPAD+ki*32+quad*8.
// B: fragment-packed w1p, lane-contiguous 1KB per wave load.
// K-loop: fully unrolled, chunks of 5 (10 loads in flight, no LDS/barriers).
// ---------------------------------------------------------------------------
__global__ __launch_bounds__(512) void gemm_kernel(
    const unsigned short* __restrict__ feats, const unsigned short* __restrict__ w1p,
    const float* __restrict__ b1, const float* __restrict__ W2,
    const float* __restrict__ b2, float* __restrict__ out) {
  __shared__ float hs[MROWS * 132];   // stride 132 keeps LDS aliasing <= 2-way
  __shared__ float ls[MROWS * 10];

  const int tid = threadIdx.x;
  const int lane = tid & 63;
  const int wave = tid >> 6;          // 0..7 = n-tile
  const int m = lane & 15;
  const int quad = lane >> 4;
  const int row0 = blockIdx.x * MROWS;

  const unsigned short* ap = feats + (size_t)(row0 + m) * KPAD + quad * 8;
  const unsigned short* bp = w1p + (size_t)wave * FRAG_ELEMS + lane * 8;

  f32x4 acc = {0.f, 0.f, 0.f, 0.f};

#pragma unroll
  for (int kc = 0; kc < 5; ++kc) {
    short8 a[5], b[5];
#pragma unroll
    for (int u = 0; u < 5; ++u) {
      const int ki = kc * 5 + u;
      a[u] = *reinterpret_cast<const short8*>(ap + ki * 32);
      b[u] = *reinterpret_cast<const short8*>(bp + ki * 512);
    }
#pragma unroll
    for (int u = 0; u < 5; ++u)
      acc = __builtin_amdgcn_mfma_f32_16x16x32_bf16(a[u], b[u], acc, 0, 0, 0);
  }

  // bias + relu -> hs  (C/D layout: col=lane&15, row=quad*4+reg)
  {
    const int col = wave * 16 + m;
    const float bc = b1[col];
#pragma unroll
    for (int r = 0; r < 4; ++r)
      hs[(quad * 4 + r) * 132 + col] = fmaxf(acc[r] + bc, 0.f);
  }
  __syncthreads();

  // GEMM2: 16 rows x 10 classes
  if (tid < MROWS * 10) {
    const int r = tid / 10;
    const int k = tid - r * 10;
    float a = b2[k];
    const float* hr = hs + r * 132;
#pragma unroll 8
    for (int jj = 0; jj < 128; ++jj) a = fmaf(hr[jj], W2[jj * 10 + k], a);
    ls[tid] = a;
  }
  __syncthreads();

  // log_softmax per row
  if (tid < MROWS) {
    const int r = tid;
    float mx = ls[r * 10];
#pragma unroll
    for (int k = 1; k < 10; ++k) mx = fmaxf(mx, ls[r * 10 + k]);
    float sum = 0.f;
#pragma unroll
    for (int k = 0; k < 10; ++k) sum += __expf(ls[r * 10 + k] - mx);
    const float lse = mx + __logf(sum);
    float* orow = out + (size_t)(row0 + r) * 10;
#pragma unroll
    for (int k = 0; k < 10; ++k) orow[k] = ls[r * 10 + k] - lse;
  }
}

extern "C" void kernel_launch(void* const* d_in, const int* in_sizes, int n_in,
                              void* d_out, int out_size, void* d_ws, size_t ws_size,
                              hipStream_t stream) {
  const float* x     = (const float*)d_in[0];
  const float* theta = (const float*)d_in[1];
  const float* W1    = (const float*)d_in[2];
  const float* b1    = (const float*)d_in[3];
  const float* W2    = (const float*)d_in[4];
  const float* b2    = (const float*)d_in[5];
  float* out = (float*)d_out;

  const int B = in_sizes[0] / 784;

  unsigned short* feats = (unsigned short*)d_ws;        // B*KPAD bf16 = 6.55 MB
  unsigned short* w1p   = feats + (size_t)B * KPAD;     // 128*KPAD bf16 = 200 KB

  w1t_pack_kernel<<<(128 * KPAD + 255) / 256, 256, 0, stream>>>(W1, w1p);
  const int total = B * PATCHES;
  quanv_kernel<<<(total + 255) / 256, 256, 0, stream>>>(x, theta, feats, total);
  gemm_kernel<<<B / MROWS, 512, 0, stream>>>(feats, w1p, b1, W2, b2, out);
}

// Round 5
// 89.487 us; speedup vs baseline: 1.2407x; 1.0430x over previous
//
#include <hip/hip_runtime.h>
#include <math.h>

#define PATCHES 196
#define KPAD 800                 // 784 padded to 25*32 for MFMA K-loop
#define MROWS 16                 // batch rows per block
#define CIRC (MROWS * PATCHES)   // 3136 circuits per block
#define FRAG_ELEMS (25 * 64 * 8) // 12800 elems per 16-row/col tile, frag order

typedef short short8 __attribute__((ext_vector_type(8)));
typedef float f32x4 __attribute__((ext_vector_type(4)));

__device__ __forceinline__ unsigned short f2bf(float f) {
  union { float f; unsigned u; } x; x.f = f;
  unsigned r = x.u + 0x7fff + ((x.u >> 16) & 1);  // round-to-nearest-even
  return (unsigned short)(r >> 16);
}

// ---------------------------------------------------------------------------
// Stage 0: pack W1^T (bf16, K zero-padded) into B-fragment order:
// elem = ntile*FRAG_ELEMS + (ki*64 + quad*16 + n15)*8 + j  (lane-contiguous)
// ---------------------------------------------------------------------------
__global__ __launch_bounds__(256) void w1t_pack_kernel(
    const float* __restrict__ W1, unsigned short* __restrict__ w1p) {
  int idx = blockIdx.x * 256 + threadIdx.x;
  if (idx >= 128 * KPAD) return;
  int n = idx / KPAD;
  int k = idx - n * KPAD;
  float v = (k < 784) ? W1[k * 128 + n] : 0.f;
  int ki = k >> 5;
  int quad = (k & 31) >> 3;
  int j = k & 7;
  w1p[(n >> 4) * FRAG_ELEMS + (ki * 64 + quad * 16 + (n & 15)) * 8 + j] = f2bf(v);
}

// ---------------------------------------------------------------------------
// Fused kernel: 256 blocks x 1024 threads (16 waves, 4 waves/SIMD).
// Phase 1: 3136 circuits -> LDS A-tile in fragment order (~3/thread).
// Phase 2: waves 0-7 MFMA GEMM1 (one 16-col n-tile each), B coalesced from
// fragment-packed global w1p. Epilogue: bias/relu -> GEMM2 -> log_softmax.
// ---------------------------------------------------------------------------
__device__ __forceinline__ void apply_ry(float st[16], int bit, float c, float s) {
#pragma unroll
  for (int i = 0; i < 16; ++i) {
    if (!(i & bit)) {
      int j = i | bit;
      float a0 = st[i], a1 = st[j];
      st[i] = c * a0 - s * a1;
      st[j] = s * a0 + c * a1;
    }
  }
}

__device__ __forceinline__ void apply_cnot(float st[16], int cb, int tb) {
#pragma unroll
  for (int i = 0; i < 16; ++i) {
    if ((i & cb) && !(i & tb)) {
      int j = i | tb;
      float t = st[i]; st[i] = st[j]; st[j] = t;
    }
  }
}

__global__ __launch_bounds__(1024) void fused_kernel(
    const float* __restrict__ x, const float* __restrict__ theta,
    const unsigned short* __restrict__ w1p, const float* __restrict__ b1,
    const float* __restrict__ W2, const float* __restrict__ b2,
    float* __restrict__ out) {
  __shared__ unsigned short afr[FRAG_ELEMS];   // 25.6 KB A tile, frag order
  __shared__ float tc[8], ts[8];
  __shared__ float hs[MROWS * 132];            // stride 132: <=2-way aliasing
  __shared__ float ls[MROWS * 10];

  const int tid = threadIdx.x;
  const int row0 = blockIdx.x * MROWS;

  if (tid < 8) {
    float a = 0.5f * theta[tid];
    tc[tid] = __cosf(a);
    ts[tid] = __sinf(a);
  }
  // zero-pad k = 784..799 (ki=24, quads 2..3) for all 16 rows
  if (tid < 64) {
    int m = tid & 15;
    int qs = tid >> 4;
    int quad = 2 + (qs >> 1);
    int j0 = (qs & 1) * 4;
    ushort4 z; z.x = z.y = z.z = z.w = 0;
    *reinterpret_cast<ushort4*>(afr + (24 * 64 + quad * 16 + m) * 8 + j0) = z;
  }
  __syncthreads();

  // ---- phase 1: circuits -> LDS (A-fragment order) ----
  for (int c = tid; c < CIRC; c += 1024) {
    int bl = c / PATCHES;              // local row 0..15
    int p = c - bl * PATCHES;
    int pr = p / 14;
    int pc = p - pr * 14;

    const float* xb = x + (size_t)(row0 + bl) * 784 + pr * 56 + pc * 2;
    float v0 = xb[0], v1 = xb[1], v2 = xb[28], v3 = xb[29];

    float st[16];
#pragma unroll
    for (int i = 0; i < 16; ++i) st[i] = 0.f;
    st[0] = 1.f;

    apply_ry(st, 8, __cosf(0.5f * v0), __sinf(0.5f * v0));
    apply_ry(st, 4, __cosf(0.5f * v1), __sinf(0.5f * v1));
    apply_ry(st, 2, __cosf(0.5f * v2), __sinf(0.5f * v2));
    apply_ry(st, 1, __cosf(0.5f * v3), __sinf(0.5f * v3));

#pragma unroll
    for (int l = 0; l < 2; ++l) {
      apply_ry(st, 8, tc[l * 4 + 0], ts[l * 4 + 0]);
      apply_ry(st, 4, tc[l * 4 + 1], ts[l * 4 + 1]);
      apply_ry(st, 2, tc[l * 4 + 2], ts[l * 4 + 2]);
      apply_ry(st, 1, tc[l * 4 + 3], ts[l * 4 + 3]);
      apply_cnot(st, 8, 4);
      apply_cnot(st, 4, 2);
      apply_cnot(st, 2, 1);
      apply_cnot(st, 1, 8);
    }

    float m0 = 0.f, m1 = 0.f, m2 = 0.f, m3 = 0.f;
#pragma unroll
    for (int i = 0; i < 16; ++i) {
      float p2 = st[i] * st[i];
      m0 += (i & 8) ? -p2 : p2;
      m1 += (i & 4) ? -p2 : p2;
      m2 += (i & 2) ? -p2 : p2;
      m3 += (i & 1) ? -p2 : p2;
    }

    // k = 4p..4p+3 for row bl -> fragment-order 8B write
    int K = p * 4;
    int ki = K >> 5;
    int quad = (K & 31) >> 3;
    int j0 = K & 7;                    // 0 or 4
    ushort4 o;
    o.x = f2bf(m0); o.y = f2bf(m1); o.z = f2bf(m2); o.w = f2bf(m3);
    *reinterpret_cast<ushort4*>(afr + (ki * 64 + quad * 16 + bl) * 8 + j0) = o;
  }
  __syncthreads();

  // ---- phase 2: MFMA K-loop, waves 0-7 (one n-tile each) ----
  const int lane = tid & 63;
  const int wave = tid >> 6;           // 0..15
  const int m = lane & 15;
  const int quad = lane >> 4;

  if (wave < 8) {
    const unsigned short* bp = w1p + (size_t)wave * FRAG_ELEMS + lane * 8;
    const unsigned short* apl = afr + lane * 8;

    f32x4 acc = {0.f, 0.f, 0.f, 0.f};

#pragma unroll
    for (int kc = 0; kc < 5; ++kc) {
      short8 a[5], b[5];
#pragma unroll
      for (int u = 0; u < 5; ++u) {
        const int ki = kc * 5 + u;
        a[u] = *reinterpret_cast<const short8*>(apl + ki * 512);
        b[u] = *reinterpret_cast<const short8*>(bp + ki * 512);
      }
#pragma unroll
      for (int u = 0; u < 5; ++u)
        acc = __builtin_amdgcn_mfma_f32_16x16x32_bf16(a[u], b[u], acc, 0, 0, 0);
    }

    // bias + relu -> hs  (C/D layout: col=lane&15, row=quad*4+reg)
    const int col = wave * 16 + m;
    const float bc = b1[col];
#pragma unroll
    for (int r = 0; r < 4; ++r)
      hs[(quad * 4 + r) * 132 + col] = fmaxf(acc[r] + bc, 0.f);
  }
  __syncthreads();

  // ---- GEMM2: 16 rows x 10 classes ----
  if (tid < MROWS * 10) {
    const int r = tid / 10;
    const int k = tid - r * 10;
    float a = b2[k];
    const float* hr = hs + r * 132;
#pragma unroll 8
    for (int jj = 0; jj < 128; ++jj) a = fmaf(hr[jj], W2[jj * 10 + k], a);
    ls[tid] = a;
  }
  __syncthreads();

  // ---- log_softmax ----
  if (tid < MROWS) {
    const int r = tid;
    float mx = ls[r * 10];
#pragma unroll
    for (int k = 1; k < 10; ++k) mx = fmaxf(mx, ls[r * 10 + k]);
    float sum = 0.f;
#pragma unroll
    for (int k = 0; k < 10; ++k) sum += __expf(ls[r * 10 + k] - mx);
    const float lse = mx + __logf(sum);
    float* orow = out + (size_t)(row0 + r) * 10;
#pragma unroll
    for (int k = 0; k < 10; ++k) orow[k] = ls[r * 10 + k] - lse;
  }
}

extern "C" void kernel_launch(void* const* d_in, const int* in_sizes, int n_in,
                              void* d_out, int out_size, void* d_ws, size_t ws_size,
                              hipStream_t stream) {
  const float* x     = (const float*)d_in[0];
  const float* theta = (const float*)d_in[1];
  const float* W1    = (const float*)d_in[2];
  const float* b1    = (const float*)d_in[3];
  const float* W2    = (const float*)d_in[4];
  const float* b2    = (const float*)d_in[5];
  float* out = (float*)d_out;

  const int B = in_sizes[0] / 784;

  unsigned short* w1p = (unsigned short*)d_ws;   // 128*KPAD bf16 = 200 KB

  w1t_pack_kernel<<<(128 * KPAD + 255) / 256, 256, 0, stream>>>(W1, w1p);
  fused_kernel<<<B / MROWS, 1024, 0, stream>>>(x, theta, w1p, b1, W2, b2, out);
}